// Round 1
// baseline (542.175 us; speedup 1.0000x reference)
//
#include <hip/hip_runtime.h>

// out[t, 0, d] = inputs[t, d]
// out[t, l, d] = memory[l, d]   (l = 1..L-1)
// T=2048, L=64, D=1024, fp32. Write-BW bound: 537 MB of stores,
// ~8.25 MB of real HBM reads. Target: pure-write stream at ~6.2 TB/s
// (proven achievable by the harness's own fillBuffer dispatch).

constexpr int T    = 2048;
constexpr int L    = 64;
constexpr int D4   = 256;        // D/4 float4 per row
constexpr int SLAB = L * D4;     // 16384 float4 per t-slab
constexpr int TT   = 16;         // t-slabs handled per block

// Block = 256 threads = one full D row (one float4 column per thread).
// Block bid -> (l = bid & 63, t-chunk = bid >> 6).
// Key idea: for l >= 1 the value is invariant across t, so load mem[l][j]
// ONCE and issue TT independent unrolled stores. Load:store goes from
// 1:1 (old kernel) to 1:16 -> near-pure store stream with deep ILP.
__global__ __launch_bounds__(256) void sliding_window_memory_kernel(
    const float4* __restrict__ in,    // [T, D4]
    const float4* __restrict__ mem,   // [L, D4]
    float4* __restrict__ out)         // [T, L, D4]
{
    const int j   = threadIdx.x;            // d4 column, 0..255
    const int bid = blockIdx.x;             // 0 .. 64*(T/TT)-1
    const int l   = bid & (L - 1);
    const int t0  = (bid >> 6) * TT;

    float4* o = out + (size_t)t0 * SLAB + l * D4 + j;

    if (l != 0) {
        // t-invariant row: one cached load, TT streaming stores.
        const float4 v = mem[l * D4 + j];
        #pragma unroll
        for (int tt = 0; tt < TT; ++tt) {
            o[tt * SLAB] = v;
        }
    } else {
        // l == 0: copy inputs[t] for each t in the chunk (independent pairs).
        const float4* ip = in + t0 * D4 + j;
        #pragma unroll
        for (int tt = 0; tt < TT; ++tt) {
            o[tt * SLAB] = ip[tt * D4];
        }
    }
}

extern "C" void kernel_launch(void* const* d_in, const int* in_sizes, int n_in,
                              void* d_out, int out_size, void* d_ws, size_t ws_size,
                              hipStream_t stream) {
    const float4* in  = (const float4*)d_in[0];   // inputs [T, D] fp32
    const float4* mem = (const float4*)d_in[1];   // memory [L, D] fp32
    float4* out = (float4*)d_out;                 // [T, L, D] fp32

    const int grid  = L * (T / TT);               // 64 * 128 = 8192 blocks
    const int block = 256;
    sliding_window_memory_kernel<<<grid, block, 0, stream>>>(in, mem, out);
}